// Round 12
// baseline (659.519 us; speedup 1.0000x reference)
//
#include <hip/hip_runtime.h>

#define BINS 10
#define TPB  256
#define NBLK 2048

// ws dword layout (62 dwords):
//  [0]      ticket (fused variant)
//  [1..10]  fused bsum    [11..20] fused bcnt    [21] fused result (float)
//  [22..31] clean bsum    [32..41] clean bcnt
//  [42..51] stage bsum    [52..61] stage bcnt
// (harness poisons ws to 0xAA before kernel_launch -> zero-kernel inits all)

__global__ __launch_bounds__(64) void ghmc_zero(unsigned* ws) {
    int i = threadIdx.x;
    if (i < 62) ws[i] = 0u;
}

// ---- r4-exact per-element form (proven 112us solo, absmax 0) ----
// t in {0,1} -> y = p*(1-2t); bce = softplus(y); bin via y >= logit(b/10).
// Cumulative sums S_b + packed 6-bit cumulative counts (<=41/lane) in cLo/cHi.
// Invalid (w==0): ye=-60 -> below all thresholds, softplus(-60)==0.0f exactly.
#define GHMC_ELEM(pk, tk, wk)                                                 \
    do {                                                                      \
        float tm_ = __builtin_fmaf((tk), -2.0f, 1.0f);                        \
        float y_  = tm_ * (pk);                                               \
        bool  v_  = ((wk) > 0.0f);                                            \
        float ye_ = v_ ? y_ : -60.0f;                                         \
        float e_  = __expf(-__builtin_fabsf(ye_));                            \
        float onep_ = 1.0f + e_;                                              \
        float bce_  = __builtin_fmaf(0.69314718055994530942f,                 \
                                     __log2f(onep_),                          \
                                     __builtin_fmaxf(ye_, 0.0f));             \
        S[0] += bce_;                                                         \
        C0   += v_ ? 1 : 0;                                                   \
        _Pragma("unroll")                                                     \
        for (int b_ = 1; b_ <= 5; ++b_) {                                     \
            bool ge_ = (ye_ >= kL[b_ - 1]);                                   \
            S[b_] += ge_ ? bce_ : 0.0f;                                       \
            cLo   += ge_ ? (1u << (6 * (b_ - 1))) : 0u;                       \
        }                                                                     \
        _Pragma("unroll")                                                     \
        for (int b_ = 6; b_ <= 9; ++b_) {                                     \
            bool ge_ = (ye_ >= kL[b_ - 1]);                                   \
            S[b_] += ge_ ? bce_ : 0.0f;                                       \
            cHi   += ge_ ? (1u << (6 * (b_ - 6))) : 0u;                       \
        }                                                                     \
    } while (0)

#define GHMC_ELEM4(P, T, W_)                                                  \
    do {                                                                      \
        GHMC_ELEM((P).x, (T).x, (W_).x);                                      \
        GHMC_ELEM((P).y, (T).y, (W_).y);                                      \
        GHMC_ELEM((P).z, (T).z, (W_).z);                                      \
        GHMC_ELEM((P).w, (T).w, (W_).w);                                      \
    } while (0)

// common accumulator declarations + logit thresholds
#define GHMC_DECLS                                                            \
    const float kL[9] = { -2.1972246f, -1.3862944f, -0.84729786f,             \
                          -0.40546511f, 0.0f, 0.40546511f, 0.84729786f,       \
                          1.3862944f, 2.1972246f };                           \
    float S[BINS];                                                            \
    _Pragma("unroll") for (int b = 0; b < BINS; ++b) S[b] = 0.0f;             \
    int C0 = 0;                                                               \
    unsigned cLo = 0u, cHi = 0u;

// r4-exact main loop: contiguous per-block chunk, depth-1 register prefetch
#define GHMC_LOOP_R4(PRED, TARG, LW, N)                                       \
    {                                                                         \
        const int nvec = (N) >> 2;                                            \
        const int start = (int)(((long long)nvec * blockIdx.x) / gridDim.x);  \
        const int end = (int)(((long long)nvec * (blockIdx.x + 1)) / gridDim.x);\
        const float4* p4 = (const float4*)(PRED);                             \
        const float4* t4 = (const float4*)(TARG);                             \
        const float4* w4 = (const float4*)(LW);                               \
        int i = start + (int)threadIdx.x;                                     \
        if (i < end) {                                                        \
            float4 p = p4[i], t = t4[i], w = w4[i];                           \
            for (int j = i + TPB; j < end; j += TPB) {                        \
                float4 pn = p4[j], tn = t4[j], wn = w4[j];                    \
                GHMC_ELEM4(p, t, w);                                          \
                p = pn; t = tn; w = wn;                                       \
            }                                                                 \
            GHMC_ELEM4(p, t, w);                                              \
        }                                                                     \
        {                                                                     \
            int rem  = (N) & 3;                                               \
            int gtid = blockIdx.x * TPB + (int)threadIdx.x;                   \
            if (gtid < rem) {                                                 \
                int idx = (nvec << 2) + gtid;                                 \
                float pk = (PRED)[idx], tk = (TARG)[idx], wk = (LW)[idx];     \
                GHMC_ELEM(pk, tk, wk);                                        \
            }                                                                 \
        }                                                                     \
    }

// cumulative -> per-bin, wave butterfly, block LDS, one global atomic per bin
#define GHMC_REDUCE(DSUM, DCNT)                                               \
    {                                                                         \
        float lsum[BINS];                                                     \
        int   lcnt[BINS];                                                     \
        int   Cc[BINS];                                                       \
        Cc[0] = C0;                                                           \
        _Pragma("unroll")                                                     \
        for (int b = 1; b <= 5; ++b) Cc[b] = (int)((cLo >> (6*(b-1))) & 63u); \
        _Pragma("unroll")                                                     \
        for (int b = 6; b <= 9; ++b) Cc[b] = (int)((cHi >> (6*(b-6))) & 63u); \
        _Pragma("unroll")                                                     \
        for (int b = 0; b < BINS - 1; ++b) {                                  \
            lsum[b] = S[b] - S[b + 1];                                        \
            lcnt[b] = Cc[b] - Cc[b + 1];                                      \
        }                                                                     \
        lsum[BINS - 1] = S[BINS - 1];                                         \
        lcnt[BINS - 1] = Cc[BINS - 1];                                        \
        __shared__ float s_bsum[BINS];                                        \
        __shared__ int   s_bcnt[BINS];                                        \
        if (threadIdx.x < BINS) {                                             \
            s_bsum[threadIdx.x] = 0.0f; s_bcnt[threadIdx.x] = 0;              \
        }                                                                     \
        __syncthreads();                                                      \
        const int lane = threadIdx.x & 63;                                    \
        _Pragma("unroll")                                                     \
        for (int b = 0; b < BINS; ++b) {                                      \
            float s = lsum[b];                                                \
            int   c = lcnt[b];                                                \
            _Pragma("unroll")                                                 \
            for (int off = 32; off > 0; off >>= 1) {                          \
                s += __shfl_xor(s, off, 64);                                  \
                c += __shfl_xor(c, off, 64);                                  \
            }                                                                 \
            if (lane == 0 && c != 0) {                                        \
                atomicAdd(&s_bsum[b], s);                                     \
                atomicAdd(&s_bcnt[b], c);                                     \
            }                                                                 \
        }                                                                     \
        __syncthreads();                                                      \
        if (threadIdx.x < BINS) {                                             \
            float s = s_bsum[threadIdx.x];                                    \
            int   c = s_bcnt[threadIdx.x];                                    \
            if (c != 0) {                                                     \
                atomicAdd(&(DSUM)[threadIdx.x], s);                           \
                atomicAdd(&(DCNT)[threadIdx.x], c);                           \
            }                                                                 \
        }                                                                     \
    }

// ---------- variant A: r4 loop + fused ticket-finalize tail (SUSPECT) -------
__global__ __launch_bounds__(256) void ghmc_fused(
    const float* __restrict__ pred, const float* __restrict__ targ,
    const float* __restrict__ lw, unsigned* __restrict__ ws, int n) {
    unsigned* ticket = ws;
    float*    bsum   = (float*)(ws + 1);
    int*      bcnt   = (int*)(ws + 11);
    float*    res    = (float*)(ws + 21);

    GHMC_DECLS
    GHMC_LOOP_R4(pred, targ, lw, n)
    GHMC_REDUCE(bsum, bcnt)

    __threadfence();
    __syncthreads();
    __shared__ int s_last;
    if (threadIdx.x == 0) {
        unsigned old = atomicAdd(ticket, 1u);
        s_last = (old == (unsigned)(gridDim.x - 1)) ? 1 : 0;
    }
    __syncthreads();
    if (s_last && threadIdx.x == 0) {
        __threadfence();
        float acc = 0.0f;
        int nb = 0;
#pragma unroll
        for (int b = 0; b < BINS; ++b) {
            int c = atomicAdd(&bcnt[b], 0);
            if (c > 0) { nb += 1; acc += atomicAdd(&bsum[b], 0.0f) / (float)c; }
        }
        res[0] = (nb > 0) ? (acc / (float)nb) : 0.0f;
    }
}

// ---------- variant B: r4 loop, r4-exact ending (CONTROL, 112us solo) --------
__global__ __launch_bounds__(256) void ghmc_clean(
    const float* __restrict__ pred, const float* __restrict__ targ,
    const float* __restrict__ lw, unsigned* __restrict__ ws, int n) {
    float* bsum = (float*)(ws + 22);
    int*   bcnt = (int*)(ws + 32);

    GHMC_DECLS
    GHMC_LOOP_R4(pred, targ, lw, n)
    GHMC_REDUCE(bsum, bcnt)
}

// ---------- variant C: r9 LDS-staging loop WITHOUT tail ----------------------
__device__ __forceinline__ void glds16(const void* g, void* l) {
    __builtin_amdgcn_global_load_lds(
        (const __attribute__((address_space(1))) void*)g,
        (__attribute__((address_space(3))) void*)l, 16, 0, 0);
}

__global__ __launch_bounds__(256) void ghmc_stage(
    const float* __restrict__ pred, const float* __restrict__ targ,
    const float* __restrict__ lw, unsigned* __restrict__ ws, int n) {
    float* bsum = (float*)(ws + 42);
    int*   bcnt = (int*)(ws + 52);

    __shared__ float4 sP[TPB];
    __shared__ float4 sT[TPB];
    __shared__ float4 sW[TPB];

    GHMC_DECLS
    {
        const int nvec = n >> 2;
        const int start = (int)(((long long)nvec * blockIdx.x) / gridDim.x);
        const int end   = (int)(((long long)nvec * (blockIdx.x + 1)) / gridDim.x);
        const int cnt4  = end - start;
        const float4* p4 = (const float4*)pred;
        const float4* t4 = (const float4*)targ;
        const float4* w4 = (const float4*)lw;
        const int wbase   = ((int)threadIdx.x >> 6) << 6;
        const int nstages = (cnt4 + TPB - 1) / TPB;
        for (int s = 0; s < nstages; ++s) {
            const int idx   = start + s * TPB + (int)threadIdx.x;
            const bool live = (idx < end);
            if (live) {
                glds16(p4 + idx, (void*)&sP[wbase]);
                glds16(t4 + idx, (void*)&sT[wbase]);
                glds16(w4 + idx, (void*)&sW[wbase]);
            }
            __syncthreads();
            if (live) {
                float4 p = sP[threadIdx.x];
                float4 t = sT[threadIdx.x];
                float4 w = sW[threadIdx.x];
                GHMC_ELEM4(p, t, w);
            }
            __syncthreads();
        }
        {
            int rem  = n & 3;
            int gtid = blockIdx.x * TPB + (int)threadIdx.x;
            if (gtid < rem) {
                int idx = (nvec << 2) + gtid;
                float pk = pred[idx], tk = targ[idx], wk = lw[idx];
                GHMC_ELEM(pk, tk, wk);
            }
        }
    }
    GHMC_REDUCE(bsum, bcnt)
}

// ---------- finalize from the CLEAN bins (authoritative output) --------------
__global__ __launch_bounds__(64) void ghmc_finalize(
    const unsigned* __restrict__ ws, float* __restrict__ out) {
    if (threadIdx.x == 0) {
        const float* bsum = (const float*)(ws + 22);
        const int*   bcnt = (const int*)(ws + 32);
        float acc = 0.0f;
        int nb = 0;
        for (int b = 0; b < BINS; ++b) {
            int c = bcnt[b];
            if (c > 0) { nb += 1; acc += bsum[b] / (float)c; }
        }
        out[0] = (nb > 0) ? (acc / (float)nb) : 0.0f;  // LOSS_WEIGHT = 1
    }
}

extern "C" void kernel_launch(void* const* d_in, const int* in_sizes, int n_in,
                              void* d_out, int out_size, void* d_ws, size_t ws_size,
                              hipStream_t stream) {
    const float* pred = (const float*)d_in[0];
    const float* targ = (const float*)d_in[1];
    const float* lw   = (const float*)d_in[2];
    float* out = (float*)d_out;
    const int n = in_sizes[0];   // 262144*80 = 20,971,520

    unsigned* ws = (unsigned*)d_ws;

    ghmc_zero<<<1, 64, 0, stream>>>(ws);
    // A: suspect (r4 loop + fused tail) -> result parked in ws[21]
    ghmc_fused<<<NBLK, TPB, 0, stream>>>(pred, targ, lw, ws, n);
    // B: control (r4-exact)
    ghmc_clean<<<NBLK, TPB, 0, stream>>>(pred, targ, lw, ws, n);
    // C: r9 LDS-staging structure, tail-free
    ghmc_stage<<<NBLK, TPB, 0, stream>>>(pred, targ, lw, ws, n);
    // authoritative output from the clean bins
    ghmc_finalize<<<1, 64, 0, stream>>>(ws, out);
}

// Round 13
// 258.988 us; speedup vs baseline: 2.5465x; 2.5465x over previous
//
#include <hip/hip_runtime.h>

#define BINS 10
#define TPB  256
#define NBLK 2048

// ======================= per-element math (r4-exact, proven) =================
// t in {0,1} -> y = p*(1-2t); bce = softplus(y); bin via y >= logit(b/10).
// Cumulative sums S_b + packed 6-bit cumulative counts (<=41/lane) in cLo/cHi.
// Invalid (w==0): ye=-60 -> below all thresholds, softplus(-60)==0.0f exactly.
#define GHMC_ELEM(pk, tk, wk)                                                 \
    do {                                                                      \
        float tm_ = __builtin_fmaf((tk), -2.0f, 1.0f);                        \
        float y_  = tm_ * (pk);                                               \
        bool  v_  = ((wk) > 0.0f);                                            \
        float ye_ = v_ ? y_ : -60.0f;                                         \
        float e_  = __expf(-__builtin_fabsf(ye_));                            \
        float onep_ = 1.0f + e_;                                              \
        float bce_  = __builtin_fmaf(0.69314718055994530942f,                 \
                                     __log2f(onep_),                          \
                                     __builtin_fmaxf(ye_, 0.0f));             \
        S[0] += bce_;                                                         \
        C0   += v_ ? 1 : 0;                                                   \
        _Pragma("unroll")                                                     \
        for (int b_ = 1; b_ <= 5; ++b_) {                                     \
            bool ge_ = (ye_ >= kL[b_ - 1]);                                   \
            S[b_] += ge_ ? bce_ : 0.0f;                                       \
            cLo   += ge_ ? (1u << (6 * (b_ - 1))) : 0u;                       \
        }                                                                     \
        _Pragma("unroll")                                                     \
        for (int b_ = 6; b_ <= 9; ++b_) {                                     \
            bool ge_ = (ye_ >= kL[b_ - 1]);                                   \
            S[b_] += ge_ ? bce_ : 0.0f;                                       \
            cHi   += ge_ ? (1u << (6 * (b_ - 6))) : 0u;                       \
        }                                                                     \
    } while (0)

#define GHMC_ELEM4(P, T, W_)                                                  \
    do {                                                                      \
        GHMC_ELEM((P).x, (T).x, (W_).x);                                      \
        GHMC_ELEM((P).y, (T).y, (W_).y);                                      \
        GHMC_ELEM((P).z, (T).z, (W_).z);                                      \
        GHMC_ELEM((P).w, (T).w, (W_).w);                                      \
    } while (0)

#define GHMC_DECLS                                                            \
    const float kL[9] = { -2.1972246f, -1.3862944f, -0.84729786f,             \
                          -0.40546511f, 0.0f, 0.40546511f, 0.84729786f,       \
                          1.3862944f, 2.1972246f };                           \
    float S[BINS];                                                            \
    _Pragma("unroll") for (int b = 0; b < BINS; ++b) S[b] = 0.0f;             \
    int C0 = 0;                                                               \
    unsigned cLo = 0u, cHi = 0u;

// cumulative -> per-bin; wave butterfly; block LDS combine -> s_bsum/s_bcnt
#define GHMC_BLOCKRED                                                         \
    float lsum[BINS];                                                         \
    int   lcnt[BINS];                                                         \
    {                                                                         \
        int Cc[BINS];                                                         \
        Cc[0] = C0;                                                           \
        _Pragma("unroll")                                                     \
        for (int b = 1; b <= 5; ++b) Cc[b] = (int)((cLo >> (6*(b-1))) & 63u); \
        _Pragma("unroll")                                                     \
        for (int b = 6; b <= 9; ++b) Cc[b] = (int)((cHi >> (6*(b-6))) & 63u); \
        _Pragma("unroll")                                                     \
        for (int b = 0; b < BINS - 1; ++b) {                                  \
            lsum[b] = S[b] - S[b + 1];                                        \
            lcnt[b] = Cc[b] - Cc[b + 1];                                      \
        }                                                                     \
        lsum[BINS - 1] = S[BINS - 1];                                         \
        lcnt[BINS - 1] = Cc[BINS - 1];                                        \
    }                                                                         \
    __shared__ float s_bsum[BINS];                                            \
    __shared__ int   s_bcnt[BINS];                                            \
    if (threadIdx.x < BINS) { s_bsum[threadIdx.x] = 0.0f;                     \
                              s_bcnt[threadIdx.x] = 0; }                      \
    __syncthreads();                                                          \
    {                                                                         \
        const int lane = threadIdx.x & 63;                                    \
        _Pragma("unroll")                                                     \
        for (int b = 0; b < BINS; ++b) {                                      \
            float s = lsum[b];                                                \
            int   c = lcnt[b];                                                \
            _Pragma("unroll")                                                 \
            for (int off = 32; off > 0; off >>= 1) {                          \
                s += __shfl_xor(s, off, 64);                                  \
                c += __shfl_xor(c, off, 64);                                  \
            }                                                                 \
            if (lane == 0 && c != 0) {                                        \
                atomicAdd(&s_bsum[b], s);                                     \
                atomicAdd(&s_bcnt[b], c);                                     \
            }                                                                 \
        }                                                                     \
    }                                                                         \
    __syncthreads();

// direct global->LDS, 16B/lane; LDS dest must be wave-uniform base (m104/m108)
__device__ __forceinline__ void glds16(const void* g, void* l) {
    __builtin_amdgcn_global_load_lds(
        (const __attribute__((address_space(1))) void*)g,
        (__attribute__((address_space(3))) void*)l, 16, 0, 0);
}

// ======================= main: T3 double-buffered staging ====================
// r12 verdict: the fused ticket/fence tail costs a CONSTANT ~270us (returning
// same-address device atomic from 2048 blocks + per-block threadfence); every
// "404us" kernel was really loop(~110)+tail(~270). Tail removed permanently.
// Output: plain stores to per-block slots (always overwritten -> no zero kernel,
// no global atomics, no fence). 2 launches total.
// Loop: unlike r9 (issue->drain->compute: zero overlap), this issues NEXT tile,
// computes CURRENT from LDS, then barrier-drains -> loads in flight during the
// whole compute phase (T3-minimum). 2x12KB buffers = 24KB LDS, 6 blocks/CU.
__global__ __launch_bounds__(256) void ghmc_main(
    const float* __restrict__ pred, const float* __restrict__ targ,
    const float* __restrict__ lw,
    float* __restrict__ slot_sum, int* __restrict__ slot_cnt, int n) {

    __shared__ float4 sP[2][TPB];
    __shared__ float4 sT[2][TPB];
    __shared__ float4 sW[2][TPB];

    GHMC_DECLS

    const int nvec  = n >> 2;
    const int start = (int)(((long long)nvec * blockIdx.x) / gridDim.x);
    const int end   = (int)(((long long)nvec * (blockIdx.x + 1)) / gridDim.x);
    const int cnt4  = end - start;

    const float4* p4 = (const float4*)pred;
    const float4* t4 = (const float4*)targ;
    const float4* w4 = (const float4*)lw;

    const int wbase   = ((int)threadIdx.x >> 6) << 6;   // wave-uniform LDS base
    const int nstages = (cnt4 + TPB - 1) / TPB;         // block-uniform

    // prologue: stage 0 -> buf 0
    {
        const int idx = start + (int)threadIdx.x;
        if (idx < end) {
            glds16(p4 + idx, (void*)&sP[0][wbase]);
            glds16(t4 + idx, (void*)&sT[0][wbase]);
            glds16(w4 + idx, (void*)&sW[0][wbase]);
        }
    }
    __syncthreads();

    int cur = 0;
    for (int s = 0; s < nstages; ++s) {
        // issue NEXT tile's loads first: in flight during compute below
        if (s + 1 < nstages) {
            const int idx = start + (s + 1) * TPB + (int)threadIdx.x;
            if (idx < end) {
                glds16(p4 + idx, (void*)&sP[cur ^ 1][wbase]);
                glds16(t4 + idx, (void*)&sT[cur ^ 1][wbase]);
                glds16(w4 + idx, (void*)&sW[cur ^ 1][wbase]);
            }
        }
        // compute CURRENT tile from LDS (lgkmcnt only; vmcnt not touched here)
        {
            const int idx = start + s * TPB + (int)threadIdx.x;
            if (idx < end) {
                float4 p = sP[cur][threadIdx.x];
                float4 t = sT[cur][threadIdx.x];
                float4 w = sW[cur][threadIdx.x];
                GHMC_ELEM4(p, t, w);
            }
        }
        __syncthreads();   // drains vmcnt: next tile landed; buffer reuse safe
        cur ^= 1;
    }

    // scalar tail (n not divisible by 4)
    {
        int rem  = n & 3;
        int gtid = blockIdx.x * TPB + (int)threadIdx.x;
        if (gtid < rem) {
            int idx = (nvec << 2) + gtid;
            float pk = pred[idx], tk = targ[idx], wk = lw[idx];
            GHMC_ELEM(pk, tk, wk);
        }
    }

    GHMC_BLOCKRED

    // plain stores to private slots, [bin][block] for coalesced finalize reads
    if (threadIdx.x < BINS) {
        slot_sum[threadIdx.x * gridDim.x + blockIdx.x] = s_bsum[threadIdx.x];
        slot_cnt[threadIdx.x * gridDim.x + blockIdx.x] = s_bcnt[threadIdx.x];
    }
}

// ======================= finalize: reduce 2048 slots =========================
__global__ __launch_bounds__(256) void ghmc_finalize(
    const float* __restrict__ slot_sum, const int* __restrict__ slot_cnt,
    float* __restrict__ out, int nblk) {
    float ps[BINS];
    int   pc[BINS];
#pragma unroll
    for (int b = 0; b < BINS; ++b) { ps[b] = 0.0f; pc[b] = 0; }
    for (int i = (int)threadIdx.x; i < nblk; i += TPB) {
#pragma unroll
        for (int b = 0; b < BINS; ++b) {
            ps[b] += slot_sum[b * nblk + i];
            pc[b] += slot_cnt[b * nblk + i];
        }
    }
    __shared__ float s_s[BINS];
    __shared__ int   s_c[BINS];
    if (threadIdx.x < BINS) { s_s[threadIdx.x] = 0.0f; s_c[threadIdx.x] = 0; }
    __syncthreads();
    const int lane = threadIdx.x & 63;
#pragma unroll
    for (int b = 0; b < BINS; ++b) {
        float s = ps[b];
        int   c = pc[b];
#pragma unroll
        for (int off = 32; off > 0; off >>= 1) {
            s += __shfl_xor(s, off, 64);
            c += __shfl_xor(c, off, 64);
        }
        if (lane == 0) { atomicAdd(&s_s[b], s); atomicAdd(&s_c[b], c); }
    }
    __syncthreads();
    if (threadIdx.x == 0) {
        float acc = 0.0f;
        int nb = 0;
        for (int b = 0; b < BINS; ++b) {
            int c = s_c[b];
            if (c > 0) { nb += 1; acc += s_s[b] / (float)c; }
        }
        out[0] = (nb > 0) ? (acc / (float)nb) : 0.0f;  // LOSS_WEIGHT = 1
    }
}

// =============== fallback (tiny ws): r4-style 3-launch atomic path ===========
__global__ __launch_bounds__(64) void ghmc_zero(unsigned* ws) {
    int i = threadIdx.x;
    if (i < 2 * BINS) ws[i] = 0u;
}

__global__ __launch_bounds__(256) void ghmc_main_atomic(
    const float* __restrict__ pred, const float* __restrict__ targ,
    const float* __restrict__ lw,
    float* __restrict__ bsum, int* __restrict__ bcnt, int n) {
    GHMC_DECLS
    const int nvec  = n >> 2;
    const int start = (int)(((long long)nvec * blockIdx.x) / gridDim.x);
    const int end   = (int)(((long long)nvec * (blockIdx.x + 1)) / gridDim.x);
    const float4* p4 = (const float4*)pred;
    const float4* t4 = (const float4*)targ;
    const float4* w4 = (const float4*)lw;
    int i = start + (int)threadIdx.x;
    if (i < end) {
        float4 p = p4[i], t = t4[i], w = w4[i];
        for (int j = i + TPB; j < end; j += TPB) {
            float4 pn = p4[j], tn = t4[j], wn = w4[j];
            GHMC_ELEM4(p, t, w);
            p = pn; t = tn; w = wn;
        }
        GHMC_ELEM4(p, t, w);
    }
    {
        int rem  = n & 3;
        int gtid = blockIdx.x * TPB + (int)threadIdx.x;
        if (gtid < rem) {
            int idx = (nvec << 2) + gtid;
            float pk = pred[idx], tk = targ[idx], wk = lw[idx];
            GHMC_ELEM(pk, tk, wk);
        }
    }
    GHMC_BLOCKRED
    if (threadIdx.x < BINS) {
        float s = s_bsum[threadIdx.x];
        int   c = s_bcnt[threadIdx.x];
        if (c != 0) {
            atomicAdd(&bsum[threadIdx.x], s);   // fire-and-forget: proven free
            atomicAdd(&bcnt[threadIdx.x], c);
        }
    }
}

__global__ __launch_bounds__(64) void ghmc_finalize_bins(
    const unsigned* __restrict__ ws, float* __restrict__ out) {
    if (threadIdx.x == 0) {
        const float* bsum = (const float*)ws;
        const int*   bcnt = (const int*)(ws + BINS);
        float acc = 0.0f;
        int nb = 0;
        for (int b = 0; b < BINS; ++b) {
            int c = bcnt[b];
            if (c > 0) { nb += 1; acc += bsum[b] / (float)c; }
        }
        out[0] = (nb > 0) ? (acc / (float)nb) : 0.0f;
    }
}

extern "C" void kernel_launch(void* const* d_in, const int* in_sizes, int n_in,
                              void* d_out, int out_size, void* d_ws, size_t ws_size,
                              hipStream_t stream) {
    const float* pred = (const float*)d_in[0];
    const float* targ = (const float*)d_in[1];
    const float* lw   = (const float*)d_in[2];
    float* out = (float*)d_out;
    const int n = in_sizes[0];   // 262144*80 = 20,971,520

    const size_t need = (size_t)NBLK * BINS * 8;   // 160 KB of slots
    if (ws_size >= need) {
        float* slot_sum = (float*)d_ws;
        int*   slot_cnt = (int*)((char*)d_ws + (size_t)NBLK * BINS * 4);
        ghmc_main<<<NBLK, TPB, 0, stream>>>(pred, targ, lw,
                                            slot_sum, slot_cnt, n);
        ghmc_finalize<<<1, TPB, 0, stream>>>(slot_sum, slot_cnt, out, NBLK);
    } else {
        unsigned* ws = (unsigned*)d_ws;
        ghmc_zero<<<1, 64, 0, stream>>>(ws);
        ghmc_main_atomic<<<NBLK, TPB, 0, stream>>>(pred, targ, lw,
                                                   (float*)ws, (int*)(ws + BINS), n);
        ghmc_finalize_bins<<<1, 64, 0, stream>>>(ws, out);
    }
}